// Round 4
// baseline (65723.700 us; speedup 1.0000x reference)
//
#include <hip/hip_runtime.h>
#include <math.h>

#define SCALE_F 0.03125f   // 1/sqrt(1024)

// =====================================================================
// fp32 tiled GEMM: C[M,N] = A[M,K] @ (BT ? B[N,K]^T : B[K,N])
// EPI: 0 = none, 1 = silu
// =====================================================================
template<bool BT, int EPI>
__global__ __launch_bounds__(256) void gemm_nt(const float* __restrict__ A,
                                               const float* __restrict__ Bm,
                                               float* __restrict__ C,
                                               int M, int N, int K) {
  __shared__ float As[32][68];
  __shared__ float Bs[32][68];
  const int tid = threadIdx.x;
  const int n0 = blockIdx.x * 64;
  const int m0 = blockIdx.y * 64;
  const int i0 = (tid >> 4) * 4;
  const int j0 = (tid & 15) * 4;
  float acc[4][4] = {};

  for (int k0 = 0; k0 < K; k0 += 32) {
#pragma unroll
    for (int s = 0; s < 2; ++s) {
      int id = tid + 256 * s;
      int r = id >> 3, c4 = id & 7;
      float4 v = *(const float4*)&A[(size_t)(m0 + r) * K + k0 + c4 * 4];
      As[c4 * 4 + 0][r] = v.x; As[c4 * 4 + 1][r] = v.y;
      As[c4 * 4 + 2][r] = v.z; As[c4 * 4 + 3][r] = v.w;
    }
    if (BT) {
#pragma unroll
      for (int s = 0; s < 2; ++s) {
        int id = tid + 256 * s;
        int r = id >> 3, c4 = id & 7;
        float4 v = *(const float4*)&Bm[(size_t)(n0 + r) * K + k0 + c4 * 4];
        Bs[c4 * 4 + 0][r] = v.x; Bs[c4 * 4 + 1][r] = v.y;
        Bs[c4 * 4 + 2][r] = v.z; Bs[c4 * 4 + 3][r] = v.w;
      }
    } else {
#pragma unroll
      for (int s = 0; s < 2; ++s) {
        int id = tid + 256 * s;
        int kk = id >> 4, c4 = id & 15;
        float4 v = *(const float4*)&Bm[(size_t)(k0 + kk) * N + n0 + c4 * 4];
        *(float4*)&Bs[kk][c4 * 4] = v;
      }
    }
    __syncthreads();
#pragma unroll
    for (int kk = 0; kk < 32; ++kk) {
      float4 a = *(const float4*)&As[kk][i0];
      float4 b = *(const float4*)&Bs[kk][j0];
      float av[4] = {a.x, a.y, a.z, a.w};
      float bv[4] = {b.x, b.y, b.z, b.w};
#pragma unroll
      for (int ii = 0; ii < 4; ++ii)
#pragma unroll
        for (int jj = 0; jj < 4; ++jj)
          acc[ii][jj] = fmaf(av[ii], bv[jj], acc[ii][jj]);
    }
    __syncthreads();
  }

#pragma unroll
  for (int ii = 0; ii < 4; ++ii) {
    float4 v;
    float* vp = (float*)&v;
#pragma unroll
    for (int jj = 0; jj < 4; ++jj) {
      float x = acc[ii][jj];
      if (EPI == 1) x = x / (1.0f + __expf(-x));
      vp[jj] = x;
    }
    *(float4*)&C[(size_t)(m0 + i0 + ii) * N + n0 + j0] = v;
  }
}

// =====================================================================
// Coherent (sc1) helpers: all cross-wg data goes through these.
// =====================================================================
__device__ __forceinline__ float ald(const float* p) {
  return __hip_atomic_load(p, __ATOMIC_RELAXED, __HIP_MEMORY_SCOPE_AGENT);
}
__device__ __forceinline__ void ast(float* p, float v) {
  __hip_atomic_store(p, v, __ATOMIC_RELAXED, __HIP_MEMORY_SCOPE_AGENT);
}
__device__ __forceinline__ int ildi(const int* p) {
  return __hip_atomic_load(p, __ATOMIC_RELAXED, __HIP_MEMORY_SCOPE_AGENT);
}

// Rotated tape addressing: row- and column-direction both conflict-free-ish.
#define TIDX(n, e) ((n) * 64 + (((e) + (n)) & 63))

// 16 register-resident float4s of weights per thread (64 floats). This fits
// UNDER the backend's observed 128-VGPR budget (~104 peak pressure). The
// previous 192-float design spilled to scratch at 100 GB/launch under the
// immovable 128 cap (3 rounds of occupancy hints all ignored).
#define REP16(M) M(0) M(1) M(2) M(3) M(4) M(5) M(6) M(7) M(8) M(9) M(10) \
  M(11) M(12) M(13) M(14) M(15)

#define WDECL(i) float4 w##i;
#define WLOAD(i) w##i = wbase4[(i)];
#define WFMA(i) { float4 hh = h4[(i)]; \
  acc = fmaf(w##i.x, hh.x, acc); acc = fmaf(w##i.y, hh.y, acc); \
  acc = fmaf(w##i.z, hh.z, acc); acc = fmaf(w##i.w, hh.w, acc); }

// =====================================================================
// Batch-local persistent scan: 256 wgs x 512 threads (1 block/CU, 8 waves).
// wg (b = wg>>4, es = wg&15) owns, for batch b only:
//   - rows [E0, E0+64) of BOTH W_h and W_write (E0 = es*64).
//     Per-thread 256-float row segment split:
//       [0,64)    registers (16 named float4)
//       [64,128)  LDS (w_lds, 128 KB)
//       [128,256) STREAMED from global every step (32 float4 loads).
//     Streamed reads hit L2/LLC: distinct weight bytes are only 8 MB
//     chip-wide (vs the spill path's 96 MB of uncacheable scratch).
//   - tape[b][all 64 n][64-e slice] in LDS (rotated layout)
//   - h slice h[b][E0..E0+64)
// => matvec output IS the slice this wg consumes: no global redistribution,
//    batches fully independent: only 16-wg batch-local syncs.
// Monotone counters: cA[b]=bar[b*16], cB[b]=bar[256+b*16]. No resets.
// =====================================================================
__global__ __launch_bounds__(512) void scan_kernel(
    const float* __restrict__ W_h, const float* __restrict__ W_wr,
    const float* __restrict__ b_h, const float* __restrict__ gate,
    float* __restrict__ wx,       // [B][T][D]; rows overwritten with h*gate
    float* __restrict__ ps_g,     // [B][16][64] score partials
    float* __restrict__ qp_g,     // [B][16]    q = h.wv partials
    float* __restrict__ h_g,      // [B][D] (= d_out h_work_f slot)
    float* __restrict__ tape_out, // [B][64][D]
    int* __restrict__ bar) {
  const int tid = threadIdx.x;
  const int wg  = blockIdx.x;
  const int b   = wg >> 4;
  const int es  = wg & 15;
  const int E0  = es * 64;
  const int wave = tid >> 6;
  const int lane = tid & 63;
  const int row  = tid >> 2;     // matvec: 128 rows (0..63 W_h, 64..127 W_wr)
  const int seg  = tid & 3;      // matvec: 256-col segment of the row
  const int nwr  = tid >> 3;     // tape mapping: slot n
  const int ksb  = tid & 7;      // tape mapping: 8-elem e-block

  __shared__ float4 w_lds[16 * 512];     // 128 KB: cols [64,128) of each seg
  __shared__ float  tape_l[64 * 64];     // 16 KB, rotated
  __shared__ float  h_lds[4 * 264];      // staged h[b], seg-padded
  __shared__ float  ws_lds[64], wa_lds[64], attn_lds[64];
  __shared__ float  wv_lds[64], Rh_lds[64], h_own[64], read_lds[64];

  // ---- weight preload: rows E0+ (row&63) of W_h (row<64) / W_wr ----
  const float* Wmat = (row < 64) ? W_h : W_wr;
  const float4* wbase4 =
      (const float4*)(Wmat + (size_t)(E0 + (row & 63)) * 1024 + seg * 256);
  REP16(WDECL)
  REP16(WLOAD)
#pragma unroll
  for (int i = 0; i < 16; ++i)
    w_lds[i * 512 + tid] = wbase4[16 + i];

  for (int i = tid; i < 4096; i += 512) tape_l[i] = 0.0f;

  float bh_r = 0.0f;
  if (wave == 0) bh_r = b_h[E0 + lane];
  __syncthreads();

  int* cA = &bar[b * 16];
  int* cB = &bar[256 + b * 16];

  // ---- prologue: h(1) = tanh(wx0 + b_h); ps (vs tape0=0) = 0 ----
  if (wave == 0) {
    size_t xi = (size_t)b * 1048576 + E0 + lane;
    float hv = tanhf(wx[xi] + bh_r);
    h_own[lane] = hv;
    ast(&h_g[b * 1024 + E0 + lane], hv);
    wx[xi] = hv * gate[xi];                 // output row 0
  }
  if (tid < 64) ast(&ps_g[b * 1024 + es * 64 + tid], 0.0f);
  __syncthreads();
  if (tid == 0) {
    asm volatile("s_waitcnt vmcnt(0) lgkmcnt(0)" ::: "memory");
    atomicAdd(cA, 1);
  }

  for (int j = 1; j <= 1024; ++j) {
    const bool last = (j == 1024);
    // ---- waitA: all 16 wgs of batch b published h(j) + ps ----
    if (tid == 0) {
      while (ildi(cA) < 16 * j) __builtin_amdgcn_s_sleep(1);
    }
    __syncthreads();

    // ---- stage h(j)[b] (2 floats/thread) ----
    {
      int d = tid * 2;
      float v0 = ald(&h_g[b * 1024 + d]);
      float v1 = ald(&h_g[b * 1024 + d + 1]);
      h_lds[(d >> 8) * 264 + (d & 255)]     = v0;
      h_lds[(d >> 8) * 264 + (d & 255) + 1] = v1;
    }
    // ws partial loads: issue early, consume after matvec
    float p0 = ald(&ps_g[b * 1024 + (ksb * 2) * 64 + nwr]);
    float p1 = ald(&ps_g[b * 1024 + (ksb * 2 + 1) * 64 + nwr]);
    // wave0 prefetch of wx/gate row j (plain cached loads)
    float wxv = 0.0f, gv = 0.0f;
    size_t xj = 0;
    if (wave == 0 && !last) {
      xj  = (size_t)b * 1048576 + (size_t)j * 1024 + E0 + lane;
      wxv = wx[xj];
      gv  = gate[xj];
    }
    __syncthreads();

    // ---- matvec: acc = W[row][seg*256 .. +256) . h[seg*256 ..) ----
    // [0,64) from registers, [64,128) from LDS, [128,256) streamed from
    // global (L2/LLC-resident read-only weights).
    float acc = 0.0f;
    {
      const float4* h4 = (const float4*)&h_lds[seg * 264];
#pragma unroll
      for (int ii = 0; ii < 32; ++ii) {
        float4 wv4 = wbase4[32 + ii];
        float4 hh = h4[32 + ii];
        acc = fmaf(wv4.x, hh.x, acc);
        acc = fmaf(wv4.y, hh.y, acc);
        acc = fmaf(wv4.z, hh.z, acc);
        acc = fmaf(wv4.w, hh.w, acc);
      }
      REP16(WFMA)
#pragma unroll
      for (int ii = 0; ii < 16; ++ii) {
        float4 hh = h4[16 + ii];
        float4 wl = w_lds[ii * 512 + tid];
        acc = fmaf(wl.x, hh.x, acc);
        acc = fmaf(wl.y, hh.y, acc);
        acc = fmaf(wl.z, hh.z, acc);
        acc = fmaf(wl.w, hh.w, acc);
      }
    }
    // ws reduce: ws[n] = sum over 16 es' partials (raw dot)
    {
      float s = p0 + p1;
      s += __shfl_xor(s, 1);
      s += __shfl_xor(s, 2);
      s += __shfl_xor(s, 4);
      if (ksb == 0) ws_lds[nwr] = s;
    }
    // matvec reduce over 4 segs (adjacent lanes)
    acc += __shfl_xor(acc, 1);
    acc += __shfl_xor(acc, 2);
    if (seg == 0) {
      if (row < 64) Rh_lds[row] = acc;
      else          wv_lds[row - 64] = acc;
    }
    __syncthreads();

    // ---- wave0: wa = softmax(SCALE*ws); publish qp partial; arriveB ----
    if (wave == 0) {
      float s = ws_lds[lane] * SCALE_F;
      float m = s;
#pragma unroll
      for (int off = 1; off < 64; off <<= 1) m = fmaxf(m, __shfl_xor(m, off));
      float ex = __expf(s - m);
      float sum = ex;
#pragma unroll
      for (int off = 1; off < 64; off <<= 1) sum += __shfl_xor(sum, off);
      wa_lds[lane] = ex / sum;
      if (!last) {
        float qp = h_own[lane] * wv_lds[lane];
#pragma unroll
        for (int off = 1; off < 64; off <<= 1) qp += __shfl_xor(qp, off);
        if (lane == 0) {
          ast(&qp_g[b * 16 + es], qp);
          asm volatile("s_waitcnt vmcnt(0)" ::: "memory");
          atomicAdd(cB, 1);
        }
      }
    }
    __syncthreads();

    // ---- tape lerp: tape(j) = tape + wa*(wv - tape) ----
    {
      float wa = wa_lds[nwr];
#pragma unroll
      for (int i = 0; i < 8; ++i) {
        int e = ksb * 8 + i;
        int idx = TIDX(nwr, e);
        float t = tape_l[idx];
        tape_l[idx] = fmaf(wa, wv_lds[e] - t, t);
      }
    }
    if (last) break;

    // ---- wave0: waitB -> q -> rs=(1-wa)ws+wa*q -> attn softmax ----
    if (wave == 0) {
      if (lane == 0) {
        while (ildi(cB) < 16 * j) __builtin_amdgcn_s_sleep(1);
      }
      asm volatile("" ::: "memory");
      float qv = (lane < 16) ? ald(&qp_g[b * 16 + lane]) : 0.0f;
      qv += __shfl_xor(qv, 1);
      qv += __shfl_xor(qv, 2);
      qv += __shfl_xor(qv, 4);
      qv += __shfl_xor(qv, 8);
      qv = __shfl(qv, 0);
      float wsr = ws_lds[lane];
      float rs = fmaf(wa_lds[lane], qv - wsr, wsr) * SCALE_F;
      float m = rs;
#pragma unroll
      for (int off = 1; off < 64; off <<= 1) m = fmaxf(m, __shfl_xor(m, off));
      float ex = __expf(rs - m);
      float sum = ex;
#pragma unroll
      for (int off = 1; off < 64; off <<= 1) sum += __shfl_xor(sum, off);
      attn_lds[lane] = ex / sum;
    }
    __syncthreads();

    // ---- gather: read[e] = sum_n attn[n]*tape(j)[n][e] ----
    {
      int ge = tid >> 3, gn = tid & 7;
      float g = 0.0f;
#pragma unroll
      for (int i = 0; i < 8; ++i) {
        int n = gn * 8 + i;
        g = fmaf(attn_lds[n], tape_l[TIDX(n, ge)], g);
      }
      g += __shfl_xor(g, 1);
      g += __shfl_xor(g, 2);
      g += __shfl_xor(g, 4);
      if (gn == 0) read_lds[ge] = g;
    }
    __syncthreads();

    // ---- h(j+1) = tanh(Rh + wx_j + read + b_h); publish + output ----
    if (wave == 0) {
      float hv = tanhf(Rh_lds[lane] + wxv + read_lds[lane] + bh_r);
      h_own[lane] = hv;
      ast(&h_g[b * 1024 + E0 + lane], hv);
      wx[xj] = hv * gv;
    }
    __syncthreads();

    // ---- ps partials vs updated tape: ps[n] = sum_own_e h(j+1).tape(j) ----
    {
      float s = 0.0f;
#pragma unroll
      for (int i = 0; i < 8; ++i) {
        int e = ksb * 8 + i;
        s = fmaf(h_own[e], tape_l[TIDX(nwr, e)], s);
      }
      s += __shfl_xor(s, 1);
      s += __shfl_xor(s, 2);
      s += __shfl_xor(s, 4);
      if (ksb == 0) ast(&ps_g[b * 1024 + es * 64 + nwr], s);
    }
    __syncthreads();
    if (tid == 0) {
      asm volatile("s_waitcnt vmcnt(0) lgkmcnt(0)" ::: "memory");
      atomicAdd(cA, 1);
    }
  }

  // ---- epilogue: dump final tape slice ----
#pragma unroll
  for (int i = 0; i < 8; ++i) {
    int e = ksb * 8 + i;
    tape_out[(size_t)(b * 64 + nwr) * 1024 + E0 + e] = tape_l[TIDX(nwr, e)];
  }
}

// =====================================================================
extern "C" void kernel_launch(void* const* d_in, const int* in_sizes, int n_in,
                              void* d_out, int out_size, void* d_ws, size_t ws_size,
                              hipStream_t stream) {
  (void)in_sizes; (void)n_in; (void)out_size; (void)ws_size;
  const float* x      = (const float*)d_in[0];
  const float* in_w   = (const float*)d_in[1];
  const float* out_w  = (const float*)d_in[2];
  const float* gate_w = (const float*)d_in[3];
  const float* W_x    = (const float*)d_in[4];
  const float* W_h    = (const float*)d_in[5];
  const float* W_wr   = (const float*)d_in[6];
  const float* b_h    = (const float*)d_in[7];

  float* out  = (float*)d_out;                     // [16][1024][1024]
  float* tape = out + (size_t)16 * 1024 * 1024;    // [16][64][1024]
  float* hfin = tape + (size_t)16 * 64 * 1024;     // [16][1024]

  float* ws = (float*)d_ws;
  // scan-time small buffers overlay M1's region (M1 dead before scan)
  float* ps_g = ws;                  // [16][16][64] = 16384 floats
  float* qp_g = ws + 16384;          // [16][16]     = 256 floats
  int*   bar  = (int*)(ws + 17408);  // 512 ints (cA: [0,256), cB: [256,512))
  float* M1   = ws;                  // [1024][1024]
  float* wx   = ws + (1 << 20);      // [16][1024][1024]

  float* gate = out;                 // park gate in d_out region

  dim3 blk(256);
  gemm_nt<false, 0><<<dim3(16, 16), blk, 0, stream>>>(W_x, in_w, M1, 1024, 1024, 1024);
  gemm_nt<true, 1><<<dim3(16, 256), blk, 0, stream>>>(x, gate_w, gate, 16384, 1024, 1024);
  gemm_nt<true, 0><<<dim3(16, 256), blk, 0, stream>>>(x, M1, wx, 16384, 1024, 1024);
  hipMemsetAsync(bar, 0, 2048, stream);
  scan_kernel<<<256, 512, 0, stream>>>(W_h, W_wr, b_h, gate, wx, ps_g, qp_g,
                                       hfin, tape, bar);
  gemm_nt<true, 0><<<dim3(16, 256), blk, 0, stream>>>(wx, out_w, out, 16384, 1024, 1024);
}

// Round 5
// 12994.789 us; speedup vs baseline: 5.0577x; 5.0577x over previous
//
#include <hip/hip_runtime.h>
#include <math.h>

#define SCALE_F 0.03125f   // 1/sqrt(1024)

// =====================================================================
// fp32 tiled GEMM: C[M,N] = A[M,K] @ (BT ? B[N,K]^T : B[K,N])
// EPI: 0 = none, 1 = silu
// =====================================================================
template<bool BT, int EPI>
__global__ __launch_bounds__(256) void gemm_nt(const float* __restrict__ A,
                                               const float* __restrict__ Bm,
                                               float* __restrict__ C,
                                               int M, int N, int K) {
  __shared__ float As[32][68];
  __shared__ float Bs[32][68];
  const int tid = threadIdx.x;
  const int n0 = blockIdx.x * 64;
  const int m0 = blockIdx.y * 64;
  const int i0 = (tid >> 4) * 4;
  const int j0 = (tid & 15) * 4;
  float acc[4][4] = {};

  for (int k0 = 0; k0 < K; k0 += 32) {
#pragma unroll
    for (int s = 0; s < 2; ++s) {
      int id = tid + 256 * s;
      int r = id >> 3, c4 = id & 7;
      float4 v = *(const float4*)&A[(size_t)(m0 + r) * K + k0 + c4 * 4];
      As[c4 * 4 + 0][r] = v.x; As[c4 * 4 + 1][r] = v.y;
      As[c4 * 4 + 2][r] = v.z; As[c4 * 4 + 3][r] = v.w;
    }
    if (BT) {
#pragma unroll
      for (int s = 0; s < 2; ++s) {
        int id = tid + 256 * s;
        int r = id >> 3, c4 = id & 7;
        float4 v = *(const float4*)&Bm[(size_t)(n0 + r) * K + k0 + c4 * 4];
        Bs[c4 * 4 + 0][r] = v.x; Bs[c4 * 4 + 1][r] = v.y;
        Bs[c4 * 4 + 2][r] = v.z; Bs[c4 * 4 + 3][r] = v.w;
      }
    } else {
#pragma unroll
      for (int s = 0; s < 2; ++s) {
        int id = tid + 256 * s;
        int kk = id >> 4, c4 = id & 15;
        float4 v = *(const float4*)&Bm[(size_t)(k0 + kk) * N + n0 + c4 * 4];
        *(float4*)&Bs[kk][c4 * 4] = v;
      }
    }
    __syncthreads();
#pragma unroll
    for (int kk = 0; kk < 32; ++kk) {
      float4 a = *(const float4*)&As[kk][i0];
      float4 b = *(const float4*)&Bs[kk][j0];
      float av[4] = {a.x, a.y, a.z, a.w};
      float bv[4] = {b.x, b.y, b.z, b.w};
#pragma unroll
      for (int ii = 0; ii < 4; ++ii)
#pragma unroll
        for (int jj = 0; jj < 4; ++jj)
          acc[ii][jj] = fmaf(av[ii], bv[jj], acc[ii][jj]);
    }
    __syncthreads();
  }

#pragma unroll
  for (int ii = 0; ii < 4; ++ii) {
    float4 v;
    float* vp = (float*)&v;
#pragma unroll
    for (int jj = 0; jj < 4; ++jj) {
      float x = acc[ii][jj];
      if (EPI == 1) x = x / (1.0f + __expf(-x));
      vp[jj] = x;
    }
    *(float4*)&C[(size_t)(m0 + i0 + ii) * N + n0 + j0] = v;
  }
}

// =====================================================================
// Coherent (agent-scope) helpers: all cross-wg data goes through these.
// =====================================================================
__device__ __forceinline__ float ald(const float* p) {
  return __hip_atomic_load(p, __ATOMIC_RELAXED, __HIP_MEMORY_SCOPE_AGENT);
}
__device__ __forceinline__ void ast(float* p, float v) {
  __hip_atomic_store(p, v, __ATOMIC_RELAXED, __HIP_MEMORY_SCOPE_AGENT);
}
__device__ __forceinline__ int ildi(const int* p) {
  return __hip_atomic_load(p, __ATOMIC_RELAXED, __HIP_MEMORY_SCOPE_AGENT);
}
__device__ __forceinline__ void iast(int* p, int v) {
  __hip_atomic_store(p, v, __ATOMIC_RELAXED, __HIP_MEMORY_SCOPE_AGENT);
}

// Rotated tape addressing: row- and column-direction both conflict-free-ish.
#define TIDX(n, e) ((n) * 64 + (((e) + (n)) & 63))

// 16 named float4 of register-resident weights per thread (64 floats).
// HARD CONSTRAINT (rounds 1-4): backend VGPR budget is 128 and immovable;
// any design needing >~100 persistent+in-flight regs spills to scratch at
// ~100 GB/launch. This kernel's loop has NO global loads besides tiny
// gathers, so peak pressure ~= 64 + working ~= 100.
#define REP16(M) M(0) M(1) M(2) M(3) M(4) M(5) M(6) M(7) M(8) M(9) M(10) \
  M(11) M(12) M(13) M(14) M(15)

#define WDECL(i) float4 w##i;
#define WLOAD(i) w##i = wb4[(i)];
#define MV(i) { float4 hh; \
  hh = *(const float4*)&hs0[4*(i)]; \
  a0=fmaf(w##i.x,hh.x,a0); a0=fmaf(w##i.y,hh.y,a0); a0=fmaf(w##i.z,hh.z,a0); a0=fmaf(w##i.w,hh.w,a0); \
  hh = *(const float4*)&hs1[4*(i)]; \
  a1=fmaf(w##i.x,hh.x,a1); a1=fmaf(w##i.y,hh.y,a1); a1=fmaf(w##i.z,hh.z,a1); a1=fmaf(w##i.w,hh.w,a1); \
  hh = *(const float4*)&hs2[4*(i)]; \
  a2=fmaf(w##i.x,hh.x,a2); a2=fmaf(w##i.y,hh.y,a2); a2=fmaf(w##i.z,hh.z,a2); a2=fmaf(w##i.w,hh.w,a2); \
  hh = *(const float4*)&hs3[4*(i)]; \
  a3=fmaf(w##i.x,hh.x,a3); a3=fmaf(w##i.y,hh.y,a3); a3=fmaf(w##i.z,hh.z,a3); a3=fmaf(w##i.w,hh.w,a3); }

// =====================================================================
// Group-shared persistent scan: 256 wgs x 512 threads.
// 4 independent GROUPS of 64 wgs; group g serves batches 4g..4g+3.
// wg = (g, b_loc, es): owner of (batch bsel=4g+b_loc, e-slice es) AND
// producer of rows R0=[es*64+b_loc*16, +16) of BOTH W_h and W_write for
// ALL 4 group batches. Weights: 64 fp32/thread in named-float4 registers
// (128 KB/wg, single copy per group -> 4 copies chip-wide, vs 16 before).
// Per step, per group: 2 sync hops, both single-writer flags polled by a
// 64-lane wave (no atomic RMW fan-in):
//   A: owners publish h(j)-slice + ps partials; flag fA[wg]=j.
//      all 64 group wgs wait fA[group]>=j; stage h (4 batches) to LDS.
//   matvec (256 FMA/thr) -> publish Rh/wv rows + qp (=h.wv) partials.
//      flag fB[wg]=j.  B: owners wait fB[group]>=j; gather own 64-row
//      Rh/wv slices + reduce 64 qp -> q; softmax via identity
//      rs=(1-wa)ws+wa*q; tape lerp; read gather; h(j+1); ps; fA=j+1.
// Barriers drain vmcnt per-wave (compiler emits waitcnt before s_barrier),
// so a flag set after __syncthreads() orders all waves' publishes.
// =====================================================================
__global__ __launch_bounds__(512) void scan_kernel(
    const float* __restrict__ W_h, const float* __restrict__ W_wr,
    const float* __restrict__ b_h, const float* __restrict__ gate,
    float* __restrict__ wx,       // [B][T][D]; rows overwritten with h*gate
    float* __restrict__ ps_g,     // [B][16][64] score partials (owner-pub)
    float* __restrict__ Rh_g,     // [B][1024]  (producer-published rows)
    float* __restrict__ wv_g,     // [B][1024]
    float* __restrict__ qp_g,     // [B][64]    q partials by in-group wg
    float* __restrict__ h_g,      // [B][D] (= d_out h_work_f slot)
    float* __restrict__ tape_out, // [B][64][D]
    int* __restrict__ flags) {    // fA[256], fB[256]
  const int tid  = threadIdx.x;
  const int wg   = blockIdx.x;
  const int g    = wg >> 6;        // group
  const int idx  = wg & 63;        // in-group index
  const int b_loc = idx >> 4;
  const int es   = idx & 15;
  const int gb   = g * 4;          // first batch of group
  const int bsel = gb + b_loc;     // owned batch
  const int E0   = es * 64;        // owned e-slice
  const int R0   = es * 64 + b_loc * 16;  // produced row base (both mats)
  const int wave = tid >> 6;
  const int lane = tid & 63;
  const int rl   = tid >> 4;       // 0..31: rl<16 -> W_h row, else W_wr
  const int cs   = tid & 15;       // 64-col segment of the row
  const int nwr  = tid >> 3;       // tape mapping: slot n
  const int ksb  = tid & 7;        // tape mapping: 8-elem e-block

  __shared__ float h_sh[4 * 1088];   // 4 batches, 16 segs x 68 (padded)
  __shared__ float tape_l[64 * 64];  // rotated, 16 KB
  __shared__ float qtmp[4][16];
  __shared__ float ws_lds[64], wa_lds[64], attn_lds[64];
  __shared__ float wv_lds[64], Rh_lds[64], h_own[64], read_lds[64];
  __shared__ float q_lds;
  // Pad LDS past 80 KB so occupancy = 1 wg/CU (256 wgs <-> 256 CUs, no
  // 2-per-CU packing imbalance). volatile store prevents elision.
  __shared__ volatile float lds_pad[12288];
  lds_pad[tid] = 0.0f;

  int* fA = flags;
  int* fB = flags + 256;

  // ---- weight preload: 16 float4 = cols [cs*64, +64) of row R0+(rl&15) ----
  const float* Wmat = (rl < 16) ? W_h : W_wr;
  const float4* wb4 =
      (const float4*)(Wmat + (size_t)(R0 + (rl & 15)) * 1024 + cs * 64);
  REP16(WDECL)
  REP16(WLOAD)

  for (int i = tid; i < 4096; i += 512) tape_l[i] = 0.0f;

  float bh_r = 0.0f;
  if (wave == 0) bh_r = b_h[E0 + lane];
  __syncthreads();

  // ---- prologue: h(1) = tanh(wx0 + b_h); ps (vs tape0=0) = 0 ----
  if (wave == 0) {
    size_t xi = (size_t)bsel * 1048576 + E0 + lane;
    float hv = tanhf(wx[xi] + bh_r);
    h_own[lane] = hv;
    ast(&h_g[bsel * 1024 + E0 + lane], hv);
    wx[xi] = hv * gate[xi];                 // output row 0
  }
  if (tid < 64) ast(&ps_g[bsel * 1024 + es * 64 + tid], 0.0f);
  __syncthreads();
  if (tid == 0) {
    asm volatile("s_waitcnt vmcnt(0) lgkmcnt(0)" ::: "memory");
    iast(&fA[wg], 1);
  }

  const float* hs0 = &h_sh[0 * 1088 + cs * 68];
  const float* hs1 = &h_sh[1 * 1088 + cs * 68];
  const float* hs2 = &h_sh[2 * 1088 + cs * 68];
  const float* hs3 = &h_sh[3 * 1088 + cs * 68];

  for (int j = 1; j <= 1024; ++j) {
    const bool last = (j == 1024);

    // ---- hop A wait: all 64 in-group wgs published h(j) + ps ----
    if (wave == 0) {
      const int* f = &fA[g * 64];
      for (;;) {
        int v = ildi(&f[lane]);
        if (__all(v >= j)) break;
        __builtin_amdgcn_s_sleep(2);
      }
    }
    __syncthreads();

    // ---- stage h(j) of 4 group batches -> LDS (8 floats/thread) ----
#pragma unroll
    for (int r = 0; r < 8; ++r) {
      int i = tid + r * 512;
      int bl = i >> 10, d = i & 1023;
      h_sh[bl * 1088 + (d >> 6) * 68 + (d & 63)] =
          ald(&h_g[(size_t)(gb + bl) * 1024 + d]);
    }
    // ps partial loads for own batch (consumed after matvec)
    float p0 = ald(&ps_g[bsel * 1024 + (ksb * 2) * 64 + nwr]);
    float p1 = ald(&ps_g[bsel * 1024 + (ksb * 2 + 1) * 64 + nwr]);
    // wave0 prefetch of wx/gate row j (plain cached loads, own rows)
    float wxv = 0.0f, gv = 0.0f;
    size_t xj = 0;
    if (wave == 0 && !last) {
      xj  = (size_t)bsel * 1048576 + (size_t)j * 1024 + E0 + lane;
      wxv = wx[xj];
      gv  = gate[xj];
    }
    __syncthreads();

    // ---- matvec: row (R0+rl&15) x 4 batches, 64-col segment ----
    float a0 = 0.0f, a1 = 0.0f, a2 = 0.0f, a3 = 0.0f;
    REP16(MV)
#pragma unroll
    for (int m = 1; m < 16; m <<= 1) {
      a0 += __shfl_xor(a0, m); a1 += __shfl_xor(a1, m);
      a2 += __shfl_xor(a2, m); a3 += __shfl_xor(a3, m);
    }
    if (cs == 0) {
      const int grow = R0 + (rl & 15);
      if (rl < 16) {
        ast(&Rh_g[(size_t)(gb + 0) * 1024 + grow], a0);
        ast(&Rh_g[(size_t)(gb + 1) * 1024 + grow], a1);
        ast(&Rh_g[(size_t)(gb + 2) * 1024 + grow], a2);
        ast(&Rh_g[(size_t)(gb + 3) * 1024 + grow], a3);
      } else {
        ast(&wv_g[(size_t)(gb + 0) * 1024 + grow], a0);
        ast(&wv_g[(size_t)(gb + 1) * 1024 + grow], a1);
        ast(&wv_g[(size_t)(gb + 2) * 1024 + grow], a2);
        ast(&wv_g[(size_t)(gb + 3) * 1024 + grow], a3);
        const int hoff = (grow >> 6) * 68 + (grow & 63);
        qtmp[0][rl - 16] = a0 * h_sh[0 * 1088 + hoff];
        qtmp[1][rl - 16] = a1 * h_sh[1 * 1088 + hoff];
        qtmp[2][rl - 16] = a2 * h_sh[2 * 1088 + hoff];
        qtmp[3][rl - 16] = a3 * h_sh[3 * 1088 + hoff];
      }
    }
    // ws reduce: ws[n] = sum over 16 owner partials (raw dot)
    {
      float s = p0 + p1;
      s += __shfl_xor(s, 1);
      s += __shfl_xor(s, 2);
      s += __shfl_xor(s, 4);
      if (ksb == 0) ws_lds[nwr] = s;
    }
    __syncthreads();

    // ---- wave0: wa = softmax(SCALE*ws); wave1: qp publish ----
    if (wave == 0) {
      float s = ws_lds[lane] * SCALE_F;
      float m = s;
#pragma unroll
      for (int off = 1; off < 64; off <<= 1) m = fmaxf(m, __shfl_xor(m, off));
      float ex = __expf(s - m);
      float sum = ex;
#pragma unroll
      for (int off = 1; off < 64; off <<= 1) sum += __shfl_xor(sum, off);
      wa_lds[lane] = ex / sum;
    } else if (wave == 1) {
      int bq = lane >> 4, k = lane & 15;
      float s = qtmp[bq][k];
      s += __shfl_xor(s, 1); s += __shfl_xor(s, 2);
      s += __shfl_xor(s, 4); s += __shfl_xor(s, 8);
      if (k == 0) ast(&qp_g[(size_t)(gb + bq) * 64 + idx], s);
    }
    __syncthreads();
    if (tid == 0) {
      asm volatile("s_waitcnt vmcnt(0) lgkmcnt(0)" ::: "memory");
      iast(&fB[wg], j);
    }

    // ---- hop B wait: all 64 in-group producers published ----
    if (wave == 0) {
      const int* f = &fB[g * 64];
      for (;;) {
        int v = ildi(&f[lane]);
        if (__all(v >= j)) break;
        __builtin_amdgcn_s_sleep(2);
      }
    }
    __syncthreads();

    // ---- gathers: own Rh/wv slices (contiguous) + q = sum of 64 qp ----
    if (wave == 2) {
      wv_lds[lane] = ald(&wv_g[(size_t)bsel * 1024 + E0 + lane]);
    } else if (wave == 3) {
      Rh_lds[lane] = ald(&Rh_g[(size_t)bsel * 1024 + E0 + lane]);
    } else if (wave == 1) {
      float qv = ald(&qp_g[(size_t)bsel * 64 + lane]);
#pragma unroll
      for (int off = 1; off < 64; off <<= 1) qv += __shfl_xor(qv, off);
      if (lane == 0) q_lds = qv;
    }
    __syncthreads();

    // ---- wave0: attn = softmax(SCALE*rs), rs via identity ----
    if (wave == 0 && !last) {
      float wsr = ws_lds[lane];
      float rs = fmaf(wa_lds[lane], q_lds - wsr, wsr) * SCALE_F;
      float m = rs;
#pragma unroll
      for (int off = 1; off < 64; off <<= 1) m = fmaxf(m, __shfl_xor(m, off));
      float ex = __expf(rs - m);
      float sum = ex;
#pragma unroll
      for (int off = 1; off < 64; off <<= 1) sum += __shfl_xor(sum, off);
      attn_lds[lane] = ex / sum;
    }
    // ---- tape lerp (all threads): tape(j) = tape + wa*(wv - tape) ----
    {
      float wa = wa_lds[nwr];
#pragma unroll
      for (int i = 0; i < 8; ++i) {
        int e = ksb * 8 + i;
        int ix = TIDX(nwr, e);
        float t = tape_l[ix];
        tape_l[ix] = fmaf(wa, wv_lds[e] - t, t);
      }
    }
    if (last) break;
    __syncthreads();

    // ---- gather: read[e] = sum_n attn[n]*tape(j)[n][e] ----
    {
      int ge = tid >> 3, gn = tid & 7;
      float gsum = 0.0f;
#pragma unroll
      for (int i = 0; i < 8; ++i) {
        int n = gn * 8 + i;
        gsum = fmaf(attn_lds[n], tape_l[TIDX(n, ge)], gsum);
      }
      gsum += __shfl_xor(gsum, 1);
      gsum += __shfl_xor(gsum, 2);
      gsum += __shfl_xor(gsum, 4);
      if (gn == 0) read_lds[ge] = gsum;
    }
    __syncthreads();

    // ---- h(j+1) = tanh(Rh + wx_j + read + b_h); publish + output ----
    if (wave == 0) {
      float hv = tanhf(Rh_lds[lane] + wxv + read_lds[lane] + bh_r);
      h_own[lane] = hv;
      ast(&h_g[bsel * 1024 + E0 + lane], hv);
      wx[xj] = hv * gv;
    }
    __syncthreads();

    // ---- ps partials vs updated tape: ps[n] = sum_own_e h(j+1).tape ----
    {
      float s = 0.0f;
#pragma unroll
      for (int i = 0; i < 8; ++i) {
        int e = ksb * 8 + i;
        s = fmaf(h_own[e], tape_l[TIDX(nwr, e)], s);
      }
      s += __shfl_xor(s, 1);
      s += __shfl_xor(s, 2);
      s += __shfl_xor(s, 4);
      if (ksb == 0) ast(&ps_g[bsel * 1024 + es * 64 + nwr], s);
    }
    __syncthreads();
    if (tid == 0) {
      asm volatile("s_waitcnt vmcnt(0) lgkmcnt(0)" ::: "memory");
      iast(&fA[wg], j + 1);
    }
  }

  // ---- epilogue: dump final tape slice ----
#pragma unroll
  for (int i = 0; i < 8; ++i) {
    int e = ksb * 8 + i;
    tape_out[(size_t)(bsel * 64 + nwr) * 1024 + E0 + e] = tape_l[TIDX(nwr, e)];
  }
}

// =====================================================================
extern "C" void kernel_launch(void* const* d_in, const int* in_sizes, int n_in,
                              void* d_out, int out_size, void* d_ws, size_t ws_size,
                              hipStream_t stream) {
  (void)in_sizes; (void)n_in; (void)out_size; (void)ws_size;
  const float* x      = (const float*)d_in[0];
  const float* in_w   = (const float*)d_in[1];
  const float* out_w  = (const float*)d_in[2];
  const float* gate_w = (const float*)d_in[3];
  const float* W_x    = (const float*)d_in[4];
  const float* W_h    = (const float*)d_in[5];
  const float* W_wr   = (const float*)d_in[6];
  const float* b_h    = (const float*)d_in[7];

  float* out  = (float*)d_out;                     // [16][1024][1024]
  float* tape = out + (size_t)16 * 1024 * 1024;    // [16][64][1024]
  float* hfin = tape + (size_t)16 * 64 * 1024;     // [16][1024]

  float* ws = (float*)d_ws;
  // scan-time small buffers overlay M1's region (M1 dead before scan)
  float* ps_g = ws;                    // [16][16][64] = 16384
  float* Rh_g = ws + 16384;            // [16][1024]   = 16384
  float* wv_g = ws + 32768;            // [16][1024]   = 16384
  float* qp_g = ws + 49152;            // [16][64]     = 1024
  int*   flg  = (int*)(ws + 50176);    // fA[256], fB[256]
  float* M1   = ws;                    // [1024][1024]
  float* wx   = ws + (1 << 20);        // [16][1024][1024]

  float* gate = out;                   // park gate in d_out region

  dim3 blk(256);
  gemm_nt<false, 0><<<dim3(16, 16), blk, 0, stream>>>(W_x, in_w, M1, 1024, 1024, 1024);
  gemm_nt<true, 1><<<dim3(16, 256), blk, 0, stream>>>(x, gate_w, gate, 16384, 1024, 1024);
  gemm_nt<true, 0><<<dim3(16, 256), blk, 0, stream>>>(x, M1, wx, 16384, 1024, 1024);
  hipMemsetAsync(flg, 0, 2048, stream);
  scan_kernel<<<256, 512, 0, stream>>>(W_h, W_wr, b_h, gate, wx, ps_g, Rh_g,
                                       wv_g, qp_g, hfin, tape, flg);
  gemm_nt<true, 0><<<dim3(16, 256), blk, 0, stream>>>(wx, out_w, out, 16384, 1024, 1024);
}